// Round 6
// baseline (263.679 us; speedup 1.0000x reference)
//
#include <hip/hip_runtime.h>
#include <math.h>

// ModifiedBarlowTwinsLoss — augmented-Gram formulation, bf16 MFMA.
// R6 = INSTRUMENTATION ROUND. Structure identical to R5 (110.3 µs), but each
// kernel's body repeats in-kernel (prep x4, gram x8, reduce x8) behind
// memory-clobber fences, so each kernel's aggregate duration exceeds the
// 42 µs harness fills and surfaces in the top-5 WITH counters.
// Per-kernel real cost = displayed dur / REPS. Output unchanged (idempotent
// repeats; reduce's atomicAdd targets scratch except on the final rep).
// Lessons: cg grid.sync ~50us/sync (R2). Cross-XCD atomic Gram fold ruinous
// (R3). Contended LDS float atomics ~15us/2048 blocks (R4->R5 confirmed).
// Launch gaps are SMALL (R5~R1) — the slack is inside the kernels.

#define NN 8192
#define DD 512
#define NC 100
#define SPLITK 16
#define NXT 10
#define NTILE 14

#define REPS_PREP 4
#define REPS_GRAM 8
#define REPS_RED  8

// ws byte offsets
#define CPS_B   0u           // cpsum [2][128 kb][512] f32 = 512 KB
#define CPQ_B   524288u      // cpsq  same = 512 KB (reused as reduce scratch)
#define MUA_B   1048576u
#define MUB_B   1050624u
#define RSA_B   1052672u
#define RSB_B   1054720u
#define CNT_B   1056768u
#define XTA_B   4194304u     // 512*8192*2
#define XTB_B   12582912u
#define MT_B    20971520u    // 128*8192*2
#define PART_B  23068672u    // 2*14*16*16384*4 (end ~52.4 MB)

typedef __attribute__((ext_vector_type(8))) short short8;
typedef __attribute__((ext_vector_type(4))) float f32x4;

__constant__ int c_ti[NTILE] = {0,0,0,0,1,1,1,2,2,3, 0,1,2,3};
__constant__ int c_tj[NTILE] = {0,1,2,3,1,2,3,2,3,3, 4,4,4,4};
__constant__ float c_w[NXT]  = {1.f,2.f,2.f,2.f,1.f,2.f,2.f,1.f,2.f,1.f};

#if defined(__has_builtin)
#if __has_builtin(__builtin_amdgcn_global_load_lds)
#define HAVE_GLL 1
#endif
#endif

#ifdef HAVE_GLL
__device__ __forceinline__ void async16(const void* g, void* l) {
    __builtin_amdgcn_global_load_lds(
        (const __attribute__((address_space(1))) void*)g,
        (__attribute__((address_space(3))) void*)l, 16, 0, 0);
}
#endif

__device__ __forceinline__ short f2bf_rne(float f) {
    unsigned int u = __builtin_bit_cast(unsigned int, f);
    u += 0x7fffu + ((u >> 16) & 1u);
    return (short)(u >> 16);
}

__device__ __forceinline__ float block_reduce_sum_p(float v, float* red) {
    int lane = threadIdx.x & 63;
    int wave = threadIdx.x >> 6;
    #pragma unroll
    for (int off = 32; off > 0; off >>= 1) v += __shfl_down(v, off, 64);
    if (lane == 0) red[wave] = v;
    __syncthreads();
    float s = 0.f;
    if (threadIdx.x == 0) {
        int nw = (blockDim.x + 63) >> 6;
        for (int w = 0; w < nw; w++) s += red[w];
    }
    return s; // thread 0 only
}

// K1: blocks 0..2047 transpose-convert + column {sum,sumsq} partials;
//     2048..2175 one-hot MT; 2176 histogram + out-zero.  Body x REPS_PREP.
__global__ __launch_bounds__(256) void k_prep(const float* __restrict__ A,
                                              const float* __restrict__ B,
                                              const int* __restrict__ labels,
                                              short* __restrict__ XTa,
                                              short* __restrict__ XTb,
                                              short* __restrict__ MT,
                                              float* __restrict__ cpsum,
                                              float* __restrict__ cpsq,
                                              int* __restrict__ counts,
                                              float* __restrict__ out) {
    __shared__ short LT[64][72];
    __shared__ float WS[4][16][4];
    __shared__ float WQ[4][16][4];
    __shared__ int hist[NC];
    int bid = blockIdx.x;
    int t = threadIdx.x;

    #pragma unroll 1
    for (int rep = 0; rep < REPS_PREP; rep++) {
        __syncthreads();
        asm volatile("" ::: "memory");
        if (bid >= 2176) {              // histogram + out zero
            if (t < NC) hist[t] = 0;
            __syncthreads();
            for (int i = t; i < NN; i += 256) atomicAdd(&hist[labels[i]], 1);
            __syncthreads();
            if (t < 128) counts[t] = (t < NC) ? hist[t] : 0;
            if (t == 0) out[0] = 0.f;
        } else if (bid >= 2048) {       // one-hot MT row
            int c = bid - 2048;
            unsigned short one = 0x3F80;
            ushort4* dst = (ushort4*)(MT + (size_t)c * NN);
            const int4* lb4 = (const int4*)labels;
            #pragma unroll
            for (int j = 0; j < 8; j++) {
                int i4 = j * 256 + t;
                int4 lb = lb4[i4];
                ushort4 v;
                v.x = (lb.x == c) ? one : (unsigned short)0;
                v.y = (lb.y == c) ? one : (unsigned short)0;
                v.z = (lb.z == c) ? one : (unsigned short)0;
                v.w = (lb.w == c) ? one : (unsigned short)0;
                dst[i4] = v;
            }
        } else {
            int mat = bid >> 10;
            const float* X = mat ? B : A;
            short* XT = mat ? XTb : XTa;
            int rem = bid & 1023;
            int c0 = (rem >> 7) << 6;
            int kb_blk = rem & 127;
            int k0 = kb_blk << 6;
            int cc = t & 15;
            int kb = t >> 4;

            float4 ps = make_float4(0.f, 0.f, 0.f, 0.f);
            float4 pq = make_float4(0.f, 0.f, 0.f, 0.f);
            #pragma unroll
            for (int s = 0; s < 4; s++) {
                int kr = kb + s * 16;
                float4 v = *(const float4*)&X[(size_t)(k0 + kr) * DD + c0 + cc * 4];
                LT[cc * 4 + 0][kr] = f2bf_rne(v.x);
                LT[cc * 4 + 1][kr] = f2bf_rne(v.y);
                LT[cc * 4 + 2][kr] = f2bf_rne(v.z);
                LT[cc * 4 + 3][kr] = f2bf_rne(v.w);
                ps.x += v.x; ps.y += v.y; ps.z += v.z; ps.w += v.w;
                pq.x += v.x * v.x; pq.y += v.y * v.y;
                pq.z += v.z * v.z; pq.w += v.w * v.w;
            }
            #pragma unroll
            for (int off = 16; off <= 32; off <<= 1) {
                ps.x += __shfl_xor(ps.x, off, 64); pq.x += __shfl_xor(pq.x, off, 64);
                ps.y += __shfl_xor(ps.y, off, 64); pq.y += __shfl_xor(pq.y, off, 64);
                ps.z += __shfl_xor(ps.z, off, 64); pq.z += __shfl_xor(pq.z, off, 64);
                ps.w += __shfl_xor(ps.w, off, 64); pq.w += __shfl_xor(pq.w, off, 64);
            }
            int wv = t >> 6, lane = t & 63;
            if (lane < 16) {
                WS[wv][lane][0] = ps.x; WS[wv][lane][1] = ps.y;
                WS[wv][lane][2] = ps.z; WS[wv][lane][3] = ps.w;
                WQ[wv][lane][0] = pq.x; WQ[wv][lane][1] = pq.y;
                WQ[wv][lane][2] = pq.z; WQ[wv][lane][3] = pq.w;
            }
            __syncthreads();

            #pragma unroll
            for (int s = 0; s < 2; s++) {
                int idx = s * 256 + t;
                int orow = idx >> 3;
                int och = idx & 7;
                *(uint4*)&XT[(size_t)(c0 + orow) * NN + k0 + och * 8] =
                    *(const uint4*)&LT[orow][och * 8];
            }
            if (t < 64) {
                int ccf = t >> 2, j = t & 3;
                float s = WS[0][ccf][j] + WS[1][ccf][j] + WS[2][ccf][j] + WS[3][ccf][j];
                float q = WQ[0][ccf][j] + WQ[1][ccf][j] + WQ[2][ccf][j] + WQ[3][ccf][j];
                size_t base = ((size_t)mat * 128 + kb_blk) * 512 + c0 + t;
                cpsum[base] = s;
                cpsq[base] = q;
            }
        }
    }
}

// K2: bf16 MFMA augmented Gram -> part; +2 stats blocks. Body x REPS_GRAM.
__global__ __launch_bounds__(256, 2) void k_gram(const short* __restrict__ XTa,
                                                 const short* __restrict__ XTb,
                                                 const short* __restrict__ MT,
                                                 float* __restrict__ part,
                                                 const float* __restrict__ cpsum,
                                                 const float* __restrict__ cpsq,
                                                 float* __restrict__ mu_a,
                                                 float* __restrict__ mu_b,
                                                 float* __restrict__ rs_a,
                                                 float* __restrict__ rs_b) {
    __shared__ short LA[2][128 * 64];
    __shared__ short LB[2][128 * 64];

    int b = blockIdx.x;
    int t = threadIdx.x;

    #pragma unroll 1
    for (int rep = 0; rep < REPS_GRAM; rep++) {
        asm volatile("" ::: "memory");
        if (b >= 448) {                  // stats fold (2 blocks)
            int mat = b - 448;
            for (int k = t; k < DD; k += 256) {
                float s = 0.f, q = 0.f;
                for (int kb = 0; kb < 128; kb++) {
                    size_t base = ((size_t)mat * 128 + kb) * 512 + k;
                    s += cpsum[base];
                    q += cpsq[base];
                }
                float mu = s * (1.0f / (float)NN);
                float var = (q - (float)NN * mu * mu) / (float)(NN - 1);
                (mat ? mu_b : mu_a)[k] = mu;
                (mat ? rs_b : rs_a)[k] = rsqrtf(var);
            }
            continue;
        }

        int xcd = b & 7;
        int idx = b >> 3;
        int grp = (idx / NTILE) * 8 + xcd;
        int tile = idx % NTILE;
        int mat = grp >> 4;
        int chunk = grp & 15;

        const short* XT = mat ? XTb : XTa;
        int ti = c_ti[tile], tj = c_tj[tile];
        const short* PA = XT + (size_t)ti * 128 * NN;
        const short* PB = (tj < 4) ? (XT + (size_t)tj * 128 * NN) : MT;
        int k0 = chunk * (NN / SPLITK);

        int wave = t >> 6, lane = t & 63;
        int quad = lane >> 4, l16 = lane & 15;
        int x7 = l16 & 7;
        int wrow = (wave >> 1) * 64, wcol = (wave & 1) * 64;

        int srow = lane >> 3;
        int sc = (lane & 7) ^ srow;

        auto stage = [&](int buf, int kk) {
            #pragma unroll
            for (int rr = 0; rr < 4; rr++) {
                int seg = wave * 4 + rr;
                int row = seg * 8 + srow;
                const short* ga = PA + (size_t)row * NN + k0 + kk + sc * 8;
                const short* gb = PB + (size_t)row * NN + k0 + kk + sc * 8;
#ifdef HAVE_GLL
                async16(ga, &LA[buf][seg * 512]);
                async16(gb, &LB[buf][seg * 512]);
#else
                *(uint4*)&LA[buf][seg * 512 + lane * 8] = *(const uint4*)ga;
                *(uint4*)&LB[buf][seg * 512 + lane * 8] = *(const uint4*)gb;
#endif
            }
        };

        f32x4 acc[4][4];
        #pragma unroll
        for (int i = 0; i < 4; i++)
            #pragma unroll
            for (int j = 0; j < 4; j++) acc[i][j] = (f32x4)0.f;

        const int KR = NN / SPLITK;
        int cur = 0;
        stage(0, 0);
        __syncthreads();

        for (int kk = 0; kk < KR; kk += 64) {
            if (kk + 64 < KR) stage(cur ^ 1, kk + 64);
            #pragma unroll
            for (int ks = 0; ks < 2; ks++) {
                short8 a[4], bfr[4];
                #pragma unroll
                for (int mt = 0; mt < 4; mt++)
                    a[mt] = *(const short8*)&LA[cur][(wrow + mt * 16 + l16) * 64 +
                                                     (((ks * 4 + quad) ^ x7) << 3)];
                #pragma unroll
                for (int nt = 0; nt < 4; nt++)
                    bfr[nt] = *(const short8*)&LB[cur][(wcol + nt * 16 + l16) * 64 +
                                                       (((ks * 4 + quad) ^ x7) << 3)];
                #pragma unroll
                for (int mt = 0; mt < 4; mt++)
                    #pragma unroll
                    for (int nt = 0; nt < 4; nt++)
                        acc[mt][nt] = __builtin_amdgcn_mfma_f32_16x16x32_bf16(
                            a[mt], bfr[nt], acc[mt][nt], 0, 0, 0);
            }
            __syncthreads();
            cur ^= 1;
        }

        float* pbase = part + ((size_t)(mat * NTILE + tile) * SPLITK + chunk) * 16384;
        #pragma unroll
        for (int mt = 0; mt < 4; mt++)
            #pragma unroll
            for (int nt = 0; nt < 4; nt++)
                #pragma unroll
                for (int rj = 0; rj < 4; rj++) {
                    int rr2 = wrow + mt * 16 + quad * 4 + rj;
                    int cc2 = wcol + nt * 16 + l16;
                    pbase[rr2 * 128 + cc2] = acc[mt][nt][rj];
                }
    }
}

// K3: fold part (both mats), apply stats, accumulate loss. Body x REPS_RED;
// reps 0..REPS_RED-2 atomicAdd into scratch, final rep into out.
__global__ __launch_bounds__(256) void k_reduce(const float* __restrict__ part,
                                                const float* __restrict__ mu_a,
                                                const float* __restrict__ mu_b,
                                                const float* __restrict__ rs_a,
                                                const float* __restrict__ rs_b,
                                                const int* __restrict__ counts,
                                                float* __restrict__ scratch,
                                                float* __restrict__ out) {
    __shared__ float red[8];
    int bid = blockIdx.x;                // 0..447
    int tile = bid >> 5, sub = bid & 31;
    int t = threadIdx.x;
    int e2 = sub * 512 + t * 2;

    #pragma unroll 1
    for (int rep = 0; rep < REPS_RED; rep++) {
        __syncthreads();
        asm volatile("" ::: "memory");
        const float2* pa = (const float2*)(part +
            ((size_t)tile * SPLITK) * 16384 + e2);
        const float2* pb = (const float2*)(part +
            ((size_t)(NTILE + tile) * SPLITK) * 16384 + e2);
        float2 Sa = make_float2(0.f, 0.f);
        float2 Sb = make_float2(0.f, 0.f);
        #pragma unroll
        for (int c = 0; c < SPLITK; c++) {
            float2 va = pa[(size_t)c * 8192];
            float2 vb = pb[(size_t)c * 8192];
            Sa.x += va.x; Sa.y += va.y;
            Sb.x += vb.x; Sb.y += vb.y;
        }

        int rw = e2 >> 7, cl = e2 & 127;
        float local = 0.f;
        float scale;
        if (tile < NXT) {
            int gi = c_ti[tile] * 128 + rw;
            int gj = c_tj[tile] * 128 + cl;
            float mai = mu_a[gi], rai = rs_a[gi];
            float mbi = mu_b[gi], rbi = rs_b[gi];
            float2 maj = *(const float2*)&mu_a[gj];
            float2 raj = *(const float2*)&rs_a[gj];
            float2 mbj = *(const float2*)&mu_b[gj];
            float2 rbj = *(const float2*)&rs_b[gj];
            float ga, gb;
            ga = rai * raj.x * (Sa.x - (float)NN * mai * maj.x);
            gb = rbi * rbj.x * (Sb.x - (float)NN * mbi * mbj.x);
            local += ga * gb;
            ga = rai * raj.y * (Sa.y - (float)NN * mai * maj.y);
            gb = rbi * rbj.y * (Sb.y - (float)NN * mbi * mbj.y);
            local += ga * gb;
            scale = c_w[tile] * (1.0f / ((float)DD * (float)DD));
        } else {
            int k = (tile - NXT) * 128 + rw;
            float mak = mu_a[k], rak = rs_a[k];
            float mbk = mu_b[k], rbk = rs_b[k];
            int2 cn = *(const int2*)&counts[cl];
            float ta, tb;
            ta = rak * (Sa.x - (float)cn.x * mak);
            tb = rbk * (Sb.x - (float)cn.x * mbk);
            local += ta * tb;
            ta = rak * (Sa.y - (float)cn.y * mak);
            tb = rbk * (Sb.y - (float)cn.y * mbk);
            local += ta * tb;
            scale = -2.0f / (float)DD;
        }

        float s = block_reduce_sum_p(local, red);
        if (t == 0) {
            float add = s * scale;
            if (bid == 0) {
                float t3 = 0.f;
                for (int cc2 = 0; cc2 < NC; cc2++) {
                    float nc = (float)counts[cc2];
                    t3 += nc * nc;
                }
                add += t3;
            }
            float* target = (rep == REPS_RED - 1) ? out : scratch;
            atomicAdd(target, add);
        }
    }
}

extern "C" void kernel_launch(void* const* d_in, const int* in_sizes, int n_in,
                              void* d_out, int out_size, void* d_ws, size_t ws_size,
                              hipStream_t stream) {
    const float* z_a = (const float*)d_in[0];
    const float* z_b = (const float*)d_in[1];
    const int* labels = (const int*)d_in[2];
    float* out = (float*)d_out;
    char* wsb = (char*)d_ws;

    float* cpsum = (float*)(wsb + CPS_B);
    float* cpsq = (float*)(wsb + CPQ_B);
    float* mu_a = (float*)(wsb + MUA_B);
    float* mu_b = (float*)(wsb + MUB_B);
    float* rs_a = (float*)(wsb + RSA_B);
    float* rs_b = (float*)(wsb + RSB_B);
    int* counts = (int*)(wsb + CNT_B);
    short* XTa = (short*)(wsb + XTA_B);
    short* XTb = (short*)(wsb + XTB_B);
    short* MT = (short*)(wsb + MT_B);
    float* part = (float*)(wsb + PART_B);

    hipLaunchKernelGGL(k_prep, dim3(2177), dim3(256), 0, stream,
                       z_a, z_b, labels, XTa, XTb, MT, cpsum, cpsq, counts, out);
    hipLaunchKernelGGL(k_gram, dim3(450), dim3(256), 0, stream,
                       XTa, XTb, MT, part, cpsum, cpsq, mu_a, mu_b, rs_a, rs_b);
    hipLaunchKernelGGL(k_reduce, dim3(448), dim3(256), 0, stream,
                       part, mu_a, mu_b, rs_a, rs_b, counts, cpsq, out);
}

// Round 7
// 160.591 us; speedup vs baseline: 1.6419x; 1.6419x over previous
//
#include <hip/hip_runtime.h>
#include <math.h>

// ModifiedBarlowTwinsLoss — augmented-Gram formulation, bf16 MFMA.
// Y = [X | M] (M = one-hot labels, 128 padded classes). One MFMA pass gives:
//   X^T X  (10 upper 128x128 tiles)  -> Gram for term1
//   X^T M  (4 tiles)                 -> per-class column sums R (term2)
// loss = (1/D^2) sum Ga~ Gb~ - (2/D) sum_c Sa~·Sb~ + sum_c n_c^2
//
// R7: 2 launches. k_reduce folded INTO k_gram via split-K last-block-done:
// per tile, 32 chunk-blocks (2 mats x 16 chunks) release-increment a counter;
// the last block acquires, spin-waits the 2 stats blocks' ready flag (all 450
// blocks co-resident -> deadlock-free), folds both mats' partials (L2/L3-hot)
// and atomicAdds the scalar loss.
// MEASURED MODEL (R6 instrumentation): dur_us carries ~80 µs of fixed harness
// re-poison (2x 256MiB fills @42 µs inside the timed window). Kernel truth:
// prep ~8 µs (BW floor), gram 14.5 µs (latency-bound: MfmaUtil 20.8%, HBM 37%,
// 0 bank conflicts), reduce ~4 µs. Controllable total ~28 µs.
// Lessons: cg grid.sync ~50µs/sync (R2). Cross-XCD atomic Gram fold ruinous
// (R3). Contended LDS float atomics ~15µs/2048 blocks (R4->R5).

#define NN 8192
#define DD 512
#define NC 100
#define SPLITK 16
#define NXT 10
#define NTILE 14

// ws byte offsets
#define CPS_B   0u           // cpsum [2][128 kb][512] f32 = 512 KB
#define CPQ_B   524288u      // cpsq  same
#define MUA_B   1048576u
#define MUB_B   1050624u
#define RSA_B   1052672u
#define RSB_B   1054720u
#define CNT_B   1056768u     // 128 i32 class counts
#define FLG_B   1057280u     // i32[16]: [0..13] tile counters, [14] stats-ready
#define XTA_B   4194304u     // 512*8192*2
#define XTB_B   12582912u
#define MT_B    20971520u    // 128*8192*2
#define PART_B  23068672u    // 2*14*16*16384*4 (end ~52.4 MB)

typedef __attribute__((ext_vector_type(8))) short short8;
typedef __attribute__((ext_vector_type(4))) float f32x4;

__constant__ int c_ti[NTILE] = {0,0,0,0,1,1,1,2,2,3, 0,1,2,3};
__constant__ int c_tj[NTILE] = {0,1,2,3,1,2,3,2,3,3, 4,4,4,4};
__constant__ float c_w[NXT]  = {1.f,2.f,2.f,2.f,1.f,2.f,2.f,1.f,2.f,1.f};

#if defined(__has_builtin)
#if __has_builtin(__builtin_amdgcn_global_load_lds)
#define HAVE_GLL 1
#endif
#endif

#ifdef HAVE_GLL
__device__ __forceinline__ void async16(const void* g, void* l) {
    __builtin_amdgcn_global_load_lds(
        (const __attribute__((address_space(1))) void*)g,
        (__attribute__((address_space(3))) void*)l, 16, 0, 0);
}
#endif

__device__ __forceinline__ short f2bf_rne(float f) {
    unsigned int u = __builtin_bit_cast(unsigned int, f);
    u += 0x7fffu + ((u >> 16) & 1u);
    return (short)(u >> 16);
}

__device__ __forceinline__ float block_reduce_sum_p(float v, float* red) {
    int lane = threadIdx.x & 63;
    int wave = threadIdx.x >> 6;
    #pragma unroll
    for (int off = 32; off > 0; off >>= 1) v += __shfl_down(v, off, 64);
    if (lane == 0) red[wave] = v;
    __syncthreads();
    float s = 0.f;
    if (threadIdx.x == 0) {
        int nw = (blockDim.x + 63) >> 6;
        for (int w = 0; w < nw; w++) s += red[w];
    }
    return s; // thread 0 only
}

// K1: blocks 0..2047 transpose-convert + column {sum,sumsq} partials (shfl
// fold); 2048..2175 one-hot MT; 2176 histogram + zero out/flags.
__global__ __launch_bounds__(256) void k_prep(const float* __restrict__ A,
                                              const float* __restrict__ B,
                                              const int* __restrict__ labels,
                                              short* __restrict__ XTa,
                                              short* __restrict__ XTb,
                                              short* __restrict__ MT,
                                              float* __restrict__ cpsum,
                                              float* __restrict__ cpsq,
                                              int* __restrict__ counts,
                                              int* __restrict__ flg,
                                              float* __restrict__ out) {
    __shared__ short LT[64][72];
    __shared__ float WS[4][16][4];
    __shared__ float WQ[4][16][4];
    __shared__ int hist[NC];
    int bid = blockIdx.x;
    int t = threadIdx.x;

    if (bid >= 2048) {
        if (bid >= 2176) {              // histogram + zero out/flags
            if (t < NC) hist[t] = 0;
            __syncthreads();
            for (int i = t; i < NN; i += 256) atomicAdd(&hist[labels[i]], 1);
            __syncthreads();
            if (t < 128) counts[t] = (t < NC) ? hist[t] : 0;
            if (t < 16) flg[t] = 0;
            if (t == 0) out[0] = 0.f;
            return;
        }
        int c = bid - 2048;             // one-hot MT row
        unsigned short one = 0x3F80;
        ushort4* dst = (ushort4*)(MT + (size_t)c * NN);
        const int4* lb4 = (const int4*)labels;
        #pragma unroll
        for (int j = 0; j < 8; j++) {
            int i4 = j * 256 + t;
            int4 lb = lb4[i4];
            ushort4 v;
            v.x = (lb.x == c) ? one : (unsigned short)0;
            v.y = (lb.y == c) ? one : (unsigned short)0;
            v.z = (lb.z == c) ? one : (unsigned short)0;
            v.w = (lb.w == c) ? one : (unsigned short)0;
            dst[i4] = v;
        }
        return;
    }

    int mat = bid >> 10;
    const float* X = mat ? B : A;
    short* XT = mat ? XTb : XTa;
    int rem = bid & 1023;
    int c0 = (rem >> 7) << 6;
    int kb_blk = rem & 127;
    int k0 = kb_blk << 6;
    int cc = t & 15;
    int kb = t >> 4;

    float4 ps = make_float4(0.f, 0.f, 0.f, 0.f);
    float4 pq = make_float4(0.f, 0.f, 0.f, 0.f);
    #pragma unroll
    for (int s = 0; s < 4; s++) {
        int kr = kb + s * 16;
        float4 v = *(const float4*)&X[(size_t)(k0 + kr) * DD + c0 + cc * 4];
        LT[cc * 4 + 0][kr] = f2bf_rne(v.x);
        LT[cc * 4 + 1][kr] = f2bf_rne(v.y);
        LT[cc * 4 + 2][kr] = f2bf_rne(v.z);
        LT[cc * 4 + 3][kr] = f2bf_rne(v.w);
        ps.x += v.x; ps.y += v.y; ps.z += v.z; ps.w += v.w;
        pq.x += v.x * v.x; pq.y += v.y * v.y;
        pq.z += v.z * v.z; pq.w += v.w * v.w;
    }
    #pragma unroll
    for (int off = 16; off <= 32; off <<= 1) {
        ps.x += __shfl_xor(ps.x, off, 64); pq.x += __shfl_xor(pq.x, off, 64);
        ps.y += __shfl_xor(ps.y, off, 64); pq.y += __shfl_xor(pq.y, off, 64);
        ps.z += __shfl_xor(ps.z, off, 64); pq.z += __shfl_xor(pq.z, off, 64);
        ps.w += __shfl_xor(ps.w, off, 64); pq.w += __shfl_xor(pq.w, off, 64);
    }
    int wv = t >> 6, lane = t & 63;
    if (lane < 16) {
        WS[wv][lane][0] = ps.x; WS[wv][lane][1] = ps.y;
        WS[wv][lane][2] = ps.z; WS[wv][lane][3] = ps.w;
        WQ[wv][lane][0] = pq.x; WQ[wv][lane][1] = pq.y;
        WQ[wv][lane][2] = pq.z; WQ[wv][lane][3] = pq.w;
    }
    __syncthreads();

    #pragma unroll
    for (int s = 0; s < 2; s++) {
        int idx = s * 256 + t;
        int orow = idx >> 3;
        int och = idx & 7;
        *(uint4*)&XT[(size_t)(c0 + orow) * NN + k0 + och * 8] =
            *(const uint4*)&LT[orow][och * 8];
    }
    if (t < 64) {
        int ccf = t >> 2, j = t & 3;
        float s = WS[0][ccf][j] + WS[1][ccf][j] + WS[2][ccf][j] + WS[3][ccf][j];
        float q = WQ[0][ccf][j] + WQ[1][ccf][j] + WQ[2][ccf][j] + WQ[3][ccf][j];
        size_t base = ((size_t)mat * 128 + kb_blk) * 512 + c0 + t;
        cpsum[base] = s;
        cpsq[base] = q;
    }
}

// K2: bf16 MFMA augmented Gram + split-K fold + loss accumulation.
// Blocks 0..447: MFMA chunks; last chunk of each tile folds + reduces.
// Blocks 448..449: column stats -> mu/rs, then release ready flag.
__global__ __launch_bounds__(256, 2) void k_gram(const short* __restrict__ XTa,
                                                 const short* __restrict__ XTb,
                                                 const short* __restrict__ MT,
                                                 float* __restrict__ part,
                                                 const float* __restrict__ cpsum,
                                                 const float* __restrict__ cpsq,
                                                 float* __restrict__ mu_a,
                                                 float* __restrict__ mu_b,
                                                 float* __restrict__ rs_a,
                                                 float* __restrict__ rs_b,
                                                 const int* __restrict__ counts,
                                                 int* __restrict__ flg,
                                                 float* __restrict__ out) {
    __shared__ short LA[2][128 * 64];
    __shared__ short LB[2][128 * 64];
    __shared__ float red[8];
    __shared__ int lastflag;

    int b = blockIdx.x;
    int t = threadIdx.x;

    if (b >= 448) {                      // stats (2 blocks) + release ready
        int mat = b - 448;
        for (int k = t; k < DD; k += 256) {
            float s = 0.f, q = 0.f;
            for (int kb = 0; kb < 128; kb++) {
                size_t base = ((size_t)mat * 128 + kb) * 512 + k;
                s += cpsum[base];
                q += cpsq[base];
            }
            float mu = s * (1.0f / (float)NN);
            float var = (q - (float)NN * mu * mu) / (float)(NN - 1);
            (mat ? mu_b : mu_a)[k] = mu;
            (mat ? rs_b : rs_a)[k] = rsqrtf(var);
        }
        __syncthreads();                 // all stores complete (vmcnt drained)
        if (t == 0) {
            __threadfence();             // write back L2 -> visible device-wide
            atomicAdd(&flg[14], 1);
        }
        return;
    }

    int xcd = b & 7;
    int idx = b >> 3;
    int grp = (idx / NTILE) * 8 + xcd;   // (mat,chunk) group
    int tile = idx % NTILE;
    int mat = grp >> 4;
    int chunk = grp & 15;

    const short* XT = mat ? XTb : XTa;
    int ti = c_ti[tile], tj = c_tj[tile];
    const short* PA = XT + (size_t)ti * 128 * NN;
    const short* PB = (tj < 4) ? (XT + (size_t)tj * 128 * NN) : MT;
    int k0 = chunk * (NN / SPLITK);

    int wave = t >> 6, lane = t & 63;
    int quad = lane >> 4, l16 = lane & 15;
    int x7 = l16 & 7;
    int wrow = (wave >> 1) * 64, wcol = (wave & 1) * 64;

    int srow = lane >> 3;
    int sc = (lane & 7) ^ srow;

    auto stage = [&](int buf, int kk) {
        #pragma unroll
        for (int rr = 0; rr < 4; rr++) {
            int seg = wave * 4 + rr;
            int row = seg * 8 + srow;
            const short* ga = PA + (size_t)row * NN + k0 + kk + sc * 8;
            const short* gb = PB + (size_t)row * NN + k0 + kk + sc * 8;
#ifdef HAVE_GLL
            async16(ga, &LA[buf][seg * 512]);
            async16(gb, &LB[buf][seg * 512]);
#else
            *(uint4*)&LA[buf][seg * 512 + lane * 8] = *(const uint4*)ga;
            *(uint4*)&LB[buf][seg * 512 + lane * 8] = *(const uint4*)gb;
#endif
        }
    };

    f32x4 acc[4][4];
    #pragma unroll
    for (int i = 0; i < 4; i++)
        #pragma unroll
        for (int j = 0; j < 4; j++) acc[i][j] = (f32x4)0.f;

    const int KR = NN / SPLITK;
    int cur = 0;
    stage(0, 0);
    __syncthreads();

    for (int kk = 0; kk < KR; kk += 64) {
        if (kk + 64 < KR) stage(cur ^ 1, kk + 64);
        #pragma unroll
        for (int ks = 0; ks < 2; ks++) {
            short8 a[4], bfr[4];
            #pragma unroll
            for (int mt = 0; mt < 4; mt++)
                a[mt] = *(const short8*)&LA[cur][(wrow + mt * 16 + l16) * 64 +
                                                 (((ks * 4 + quad) ^ x7) << 3)];
            #pragma unroll
            for (int nt = 0; nt < 4; nt++)
                bfr[nt] = *(const short8*)&LB[cur][(wcol + nt * 16 + l16) * 64 +
                                                   (((ks * 4 + quad) ^ x7) << 3)];
            #pragma unroll
            for (int mt = 0; mt < 4; mt++)
                #pragma unroll
                for (int nt = 0; nt < 4; nt++)
                    acc[mt][nt] = __builtin_amdgcn_mfma_f32_16x16x32_bf16(
                        a[mt], bfr[nt], acc[mt][nt], 0, 0, 0);
        }
        __syncthreads();
        cur ^= 1;
    }

    float* pbase = part + ((size_t)(mat * NTILE + tile) * SPLITK + chunk) * 16384;
    #pragma unroll
    for (int mt = 0; mt < 4; mt++)
        #pragma unroll
        for (int nt = 0; nt < 4; nt++)
            #pragma unroll
            for (int rj = 0; rj < 4; rj++) {
                int rr2 = wrow + mt * 16 + quad * 4 + rj;
                int cc2 = wcol + nt * 16 + l16;
                pbase[rr2 * 128 + cc2] = acc[mt][nt][rj];
            }

    // ---- split-K last-block-done fold ----
    __syncthreads();                     // all part stores complete (vmcnt=0)
    if (t == 0) {
        __threadfence();                 // release: part visible device-wide
        int old = atomicAdd(&flg[tile], 1);
        lastflag = (old == 2 * SPLITK - 1);
    }
    __syncthreads();
    if (!lastflag) return;

    // last block for this tile: wait for stats, then fold both mats + reduce
    if (t == 0) {
        while (__hip_atomic_load(&flg[14], __ATOMIC_ACQUIRE,
                                 __HIP_MEMORY_SCOPE_AGENT) < 2)
            __builtin_amdgcn_s_sleep(8);
    }
    __syncthreads();
    __threadfence();                     // acquire: invalidate stale L2 lines

    const float* pA = part + ((size_t)(0 * NTILE + tile) * SPLITK) * 16384;
    const float* pB = part + ((size_t)(1 * NTILE + tile) * SPLITK) * 16384;
    float local = 0.f;
    float scale;
    if (tile < NXT) scale = c_w[tile] * (1.0f / ((float)DD * (float)DD));
    else            scale = -2.0f / (float)DD;

    #pragma unroll 1
    for (int sub = 0; sub < 32; sub++) {
        int e2 = sub * 512 + t * 2;
        float2 Sa = make_float2(0.f, 0.f);
        float2 Sb = make_float2(0.f, 0.f);
        #pragma unroll
        for (int c = 0; c < SPLITK; c++) {
            float2 va = *(const float2*)&pA[(size_t)c * 16384 + e2];
            float2 vb = *(const float2*)&pB[(size_t)c * 16384 + e2];
            Sa.x += va.x; Sa.y += va.y;
            Sb.x += vb.x; Sb.y += vb.y;
        }
        int rw = e2 >> 7, cl = e2 & 127;
        if (tile < NXT) {
            int gi = c_ti[tile] * 128 + rw;
            int gj = c_tj[tile] * 128 + cl;
            float mai = mu_a[gi], rai = rs_a[gi];
            float mbi = mu_b[gi], rbi = rs_b[gi];
            float2 maj = *(const float2*)&mu_a[gj];
            float2 raj = *(const float2*)&rs_a[gj];
            float2 mbj = *(const float2*)&mu_b[gj];
            float2 rbj = *(const float2*)&rs_b[gj];
            float ga, gb;
            ga = rai * raj.x * (Sa.x - (float)NN * mai * maj.x);
            gb = rbi * rbj.x * (Sb.x - (float)NN * mbi * mbj.x);
            local += ga * gb;
            ga = rai * raj.y * (Sa.y - (float)NN * mai * maj.y);
            gb = rbi * rbj.y * (Sb.y - (float)NN * mbi * mbj.y);
            local += ga * gb;
        } else {
            int k = (tile - NXT) * 128 + rw;
            float mak = mu_a[k], rak = rs_a[k];
            float mbk = mu_b[k], rbk = rs_b[k];
            int2 cn = *(const int2*)&counts[cl];
            float ta, tb;
            ta = rak * (Sa.x - (float)cn.x * mak);
            tb = rbk * (Sb.x - (float)cn.x * mbk);
            local += ta * tb;
            ta = rak * (Sa.y - (float)cn.y * mak);
            tb = rbk * (Sb.y - (float)cn.y * mbk);
            local += ta * tb;
        }
    }

    float s = block_reduce_sum_p(local, red);
    if (t == 0) {
        float add = s * scale;
        if (tile == 0) {
            float t3 = 0.f;
            for (int cc2 = 0; cc2 < NC; cc2++) {
                float nc = (float)counts[cc2];
                t3 += nc * nc;
            }
            add += t3;
        }
        atomicAdd(out, add);
    }
}

extern "C" void kernel_launch(void* const* d_in, const int* in_sizes, int n_in,
                              void* d_out, int out_size, void* d_ws, size_t ws_size,
                              hipStream_t stream) {
    const float* z_a = (const float*)d_in[0];
    const float* z_b = (const float*)d_in[1];
    const int* labels = (const int*)d_in[2];
    float* out = (float*)d_out;
    char* wsb = (char*)d_ws;

    float* cpsum = (float*)(wsb + CPS_B);
    float* cpsq = (float*)(wsb + CPQ_B);
    float* mu_a = (float*)(wsb + MUA_B);
    float* mu_b = (float*)(wsb + MUB_B);
    float* rs_a = (float*)(wsb + RSA_B);
    float* rs_b = (float*)(wsb + RSB_B);
    int* counts = (int*)(wsb + CNT_B);
    int* flg = (int*)(wsb + FLG_B);
    short* XTa = (short*)(wsb + XTA_B);
    short* XTb = (short*)(wsb + XTB_B);
    short* MT = (short*)(wsb + MT_B);
    float* part = (float*)(wsb + PART_B);

    hipLaunchKernelGGL(k_prep, dim3(2177), dim3(256), 0, stream,
                       z_a, z_b, labels, XTa, XTb, MT, cpsum, cpsq,
                       counts, flg, out);
    hipLaunchKernelGGL(k_gram, dim3(450), dim3(256), 0, stream,
                       XTa, XTb, MT, part, cpsum, cpsq,
                       mu_a, mu_b, rs_a, rs_b, counts, flg, out);
}

// Round 8
// 109.256 us; speedup vs baseline: 2.4134x; 1.4699x over previous
//
#include <hip/hip_runtime.h>
#include <math.h>

// ModifiedBarlowTwinsLoss — augmented-Gram formulation, bf16 MFMA.
// Y = [X | M] (M = one-hot labels, 128 padded classes). One MFMA pass gives:
//   X^T X  (10 upper 128x128 tiles)  -> Gram for term1
//   X^T M  (4 tiles)                 -> per-class column sums R (term2)
// loss = (1/D^2) sum Ga~ Gb~ - (2/D) sum_c Sa~·Sb~ + sum_c n_c^2
//
// R8 = R5 revert (best verified: 110.3 µs) + s_setprio around gram's MFMA
// cluster (T5; 2 independent blocks/CU -> wave role diversity -> arbitration
// can favor MFMA waves; worst observed cost ~1%).
//
// MEASURED MODEL (R6 instrumentation + R7 failure):
//   dur_us = ~80 µs FIXED harness re-poison (2x 256MiB fills @42 µs inside
//   the timed window; confirmed by R2/R6/R7 residues)
//          + prep ~8-10 µs (at BW floor: ~67 MB moved)
//          + gram ~14.5 µs (latency-bound: MfmaUtil 20.8% = 517 TF, HBM 37%,
//            0 bank conflicts, 2 blocks/CU)
//          + reduce ~4-5 µs (29 MB L3-hot fold, at floor)
//          + ~2-4 µs launch gaps.
// Lessons: cg grid.sync ~50µs/sync (R2). Cross-XCD atomic Gram fold ruinous
// (R3). Contended LDS float atomics ~15µs/2048 blocks (R4->R5). Last-block
// split-K fold concentrates 28 MB on 14 blocks -> ~100 µs tail (R7): folds
// must stay wide (448 blocks).

#define NN 8192
#define DD 512
#define NC 100
#define SPLITK 16
#define NXT 10
#define NTILE 14

// ws byte offsets
#define CPS_B   0u           // cpsum [2][128 kb][512] f32 = 512 KB
#define CPQ_B   524288u      // cpsq  same = 512 KB
#define MUA_B   1048576u
#define MUB_B   1050624u
#define RSA_B   1052672u
#define RSB_B   1054720u
#define CNT_B   1056768u
#define XTA_B   4194304u     // 512*8192*2
#define XTB_B   12582912u
#define MT_B    20971520u    // 128*8192*2
#define PART_B  23068672u    // 2*14*16*16384*4 (end ~52.4 MB)

typedef __attribute__((ext_vector_type(8))) short short8;
typedef __attribute__((ext_vector_type(4))) float f32x4;

__constant__ int c_ti[NTILE] = {0,0,0,0,1,1,1,2,2,3, 0,1,2,3};
__constant__ int c_tj[NTILE] = {0,1,2,3,1,2,3,2,3,3, 4,4,4,4};
__constant__ float c_w[NXT]  = {1.f,2.f,2.f,2.f,1.f,2.f,2.f,1.f,2.f,1.f};

#if defined(__has_builtin)
#if __has_builtin(__builtin_amdgcn_global_load_lds)
#define HAVE_GLL 1
#endif
#endif

#ifdef HAVE_GLL
__device__ __forceinline__ void async16(const void* g, void* l) {
    __builtin_amdgcn_global_load_lds(
        (const __attribute__((address_space(1))) void*)g,
        (__attribute__((address_space(3))) void*)l, 16, 0, 0);
}
#endif

__device__ __forceinline__ short f2bf_rne(float f) {
    unsigned int u = __builtin_bit_cast(unsigned int, f);
    u += 0x7fffu + ((u >> 16) & 1u);
    return (short)(u >> 16);
}

__device__ __forceinline__ float block_reduce_sum_p(float v, float* red) {
    int lane = threadIdx.x & 63;
    int wave = threadIdx.x >> 6;
    #pragma unroll
    for (int off = 32; off > 0; off >>= 1) v += __shfl_down(v, off, 64);
    if (lane == 0) red[wave] = v;
    __syncthreads();
    float s = 0.f;
    if (threadIdx.x == 0) {
        int nw = (blockDim.x + 63) >> 6;
        for (int w = 0; w < nw; w++) s += red[w];
    }
    return s; // thread 0 only
}

// K1: blocks 0..2047 transpose-convert f32->bf16 + per-column {sum,sumsq}
//     partials (shfl fold, no atomics); 2048..2175 one-hot MT;
//     2176 histogram + out-zero.
__global__ __launch_bounds__(256) void k_prep(const float* __restrict__ A,
                                              const float* __restrict__ B,
                                              const int* __restrict__ labels,
                                              short* __restrict__ XTa,
                                              short* __restrict__ XTb,
                                              short* __restrict__ MT,
                                              float* __restrict__ cpsum,
                                              float* __restrict__ cpsq,
                                              int* __restrict__ counts,
                                              float* __restrict__ out) {
    __shared__ short LT[64][72];
    __shared__ float WS[4][16][4];
    __shared__ float WQ[4][16][4];
    __shared__ int hist[NC];
    int bid = blockIdx.x;
    int t = threadIdx.x;

    if (bid >= 2048) {
        if (bid >= 2176) {              // histogram + out zero
            if (t < NC) hist[t] = 0;
            __syncthreads();
            for (int i = t; i < NN; i += 256) atomicAdd(&hist[labels[i]], 1);
            __syncthreads();
            if (t < 128) counts[t] = (t < NC) ? hist[t] : 0;
            if (t == 0) out[0] = 0.f;
            return;
        }
        int c = bid - 2048;             // one-hot MT row
        unsigned short one = 0x3F80;
        ushort4* dst = (ushort4*)(MT + (size_t)c * NN);
        const int4* lb4 = (const int4*)labels;
        #pragma unroll
        for (int j = 0; j < 8; j++) {
            int i4 = j * 256 + t;
            int4 lb = lb4[i4];
            ushort4 v;
            v.x = (lb.x == c) ? one : (unsigned short)0;
            v.y = (lb.y == c) ? one : (unsigned short)0;
            v.z = (lb.z == c) ? one : (unsigned short)0;
            v.w = (lb.w == c) ? one : (unsigned short)0;
            dst[i4] = v;
        }
        return;
    }

    int mat = bid >> 10;
    const float* X = mat ? B : A;
    short* XT = mat ? XTb : XTa;
    int rem = bid & 1023;
    int c0 = (rem >> 7) << 6;
    int kb_blk = rem & 127;
    int k0 = kb_blk << 6;
    int cc = t & 15;
    int kb = t >> 4;

    float4 ps = make_float4(0.f, 0.f, 0.f, 0.f);
    float4 pq = make_float4(0.f, 0.f, 0.f, 0.f);
    #pragma unroll
    for (int s = 0; s < 4; s++) {
        int kr = kb + s * 16;
        float4 v = *(const float4*)&X[(size_t)(k0 + kr) * DD + c0 + cc * 4];
        LT[cc * 4 + 0][kr] = f2bf_rne(v.x);
        LT[cc * 4 + 1][kr] = f2bf_rne(v.y);
        LT[cc * 4 + 2][kr] = f2bf_rne(v.z);
        LT[cc * 4 + 3][kr] = f2bf_rne(v.w);
        ps.x += v.x; ps.y += v.y; ps.z += v.z; ps.w += v.w;
        pq.x += v.x * v.x; pq.y += v.y * v.y;
        pq.z += v.z * v.z; pq.w += v.w * v.w;
    }
    #pragma unroll
    for (int off = 16; off <= 32; off <<= 1) {
        ps.x += __shfl_xor(ps.x, off, 64); pq.x += __shfl_xor(pq.x, off, 64);
        ps.y += __shfl_xor(ps.y, off, 64); pq.y += __shfl_xor(pq.y, off, 64);
        ps.z += __shfl_xor(ps.z, off, 64); pq.z += __shfl_xor(pq.z, off, 64);
        ps.w += __shfl_xor(ps.w, off, 64); pq.w += __shfl_xor(pq.w, off, 64);
    }
    int wv = t >> 6, lane = t & 63;
    if (lane < 16) {
        WS[wv][lane][0] = ps.x; WS[wv][lane][1] = ps.y;
        WS[wv][lane][2] = ps.z; WS[wv][lane][3] = ps.w;
        WQ[wv][lane][0] = pq.x; WQ[wv][lane][1] = pq.y;
        WQ[wv][lane][2] = pq.z; WQ[wv][lane][3] = pq.w;
    }
    __syncthreads();

    #pragma unroll
    for (int s = 0; s < 2; s++) {
        int idx = s * 256 + t;
        int orow = idx >> 3;
        int och = idx & 7;
        *(uint4*)&XT[(size_t)(c0 + orow) * NN + k0 + och * 8] =
            *(const uint4*)&LT[orow][och * 8];
    }
    if (t < 64) {
        int ccf = t >> 2, j = t & 3;
        float s = WS[0][ccf][j] + WS[1][ccf][j] + WS[2][ccf][j] + WS[3][ccf][j];
        float q = WQ[0][ccf][j] + WQ[1][ccf][j] + WQ[2][ccf][j] + WQ[3][ccf][j];
        size_t base = ((size_t)mat * 128 + kb_blk) * 512 + c0 + t;
        cpsum[base] = s;
        cpsq[base] = q;
    }
}

// K2: bf16 MFMA augmented Gram -> part (split-K partials, no atomics).
// 448 MFMA blocks + 2 stats blocks. Double-buffered LDS, XOR swizzle, XCD
// grouping. setprio(1) around the MFMA cluster (T5).
__global__ __launch_bounds__(256, 2) void k_gram(const short* __restrict__ XTa,
                                                 const short* __restrict__ XTb,
                                                 const short* __restrict__ MT,
                                                 float* __restrict__ part,
                                                 const float* __restrict__ cpsum,
                                                 const float* __restrict__ cpsq,
                                                 float* __restrict__ mu_a,
                                                 float* __restrict__ mu_b,
                                                 float* __restrict__ rs_a,
                                                 float* __restrict__ rs_b) {
    __shared__ short LA[2][128 * 64];
    __shared__ short LB[2][128 * 64];

    int b = blockIdx.x;
    int t = threadIdx.x;

    if (b >= 448) {                      // stats fold (2 blocks)
        int mat = b - 448;
        for (int k = t; k < DD; k += 256) {
            float s = 0.f, q = 0.f;
            for (int kb = 0; kb < 128; kb++) {
                size_t base = ((size_t)mat * 128 + kb) * 512 + k;
                s += cpsum[base];
                q += cpsq[base];
            }
            float mu = s * (1.0f / (float)NN);
            float var = (q - (float)NN * mu * mu) / (float)(NN - 1);
            (mat ? mu_b : mu_a)[k] = mu;
            (mat ? rs_b : rs_a)[k] = rsqrtf(var);
        }
        return;
    }

    int xcd = b & 7;
    int idx = b >> 3;
    int grp = (idx / NTILE) * 8 + xcd;
    int tile = idx % NTILE;
    int mat = grp >> 4;
    int chunk = grp & 15;

    const short* XT = mat ? XTb : XTa;
    int ti = c_ti[tile], tj = c_tj[tile];
    const short* PA = XT + (size_t)ti * 128 * NN;
    const short* PB = (tj < 4) ? (XT + (size_t)tj * 128 * NN) : MT;
    int k0 = chunk * (NN / SPLITK);

    int wave = t >> 6, lane = t & 63;
    int quad = lane >> 4, l16 = lane & 15;
    int x7 = l16 & 7;
    int wrow = (wave >> 1) * 64, wcol = (wave & 1) * 64;

    int srow = lane >> 3;
    int sc = (lane & 7) ^ srow;

    auto stage = [&](int buf, int kk) {
        #pragma unroll
        for (int rr = 0; rr < 4; rr++) {
            int seg = wave * 4 + rr;
            int row = seg * 8 + srow;
            const short* ga = PA + (size_t)row * NN + k0 + kk + sc * 8;
            const short* gb = PB + (size_t)row * NN + k0 + kk + sc * 8;
#ifdef HAVE_GLL
            async16(ga, &LA[buf][seg * 512]);
            async16(gb, &LB[buf][seg * 512]);
#else
            *(uint4*)&LA[buf][seg * 512 + lane * 8] = *(const uint4*)ga;
            *(uint4*)&LB[buf][seg * 512 + lane * 8] = *(const uint4*)gb;
#endif
        }
    };

    f32x4 acc[4][4];
    #pragma unroll
    for (int i = 0; i < 4; i++)
        #pragma unroll
        for (int j = 0; j < 4; j++) acc[i][j] = (f32x4)0.f;

    const int KR = NN / SPLITK;
    int cur = 0;
    stage(0, 0);
    __syncthreads();

    for (int kk = 0; kk < KR; kk += 64) {
        if (kk + 64 < KR) stage(cur ^ 1, kk + 64);
        #pragma unroll
        for (int ks = 0; ks < 2; ks++) {
            short8 a[4], bfr[4];
            #pragma unroll
            for (int mt = 0; mt < 4; mt++)
                a[mt] = *(const short8*)&LA[cur][(wrow + mt * 16 + l16) * 64 +
                                                 (((ks * 4 + quad) ^ x7) << 3)];
            #pragma unroll
            for (int nt = 0; nt < 4; nt++)
                bfr[nt] = *(const short8*)&LB[cur][(wcol + nt * 16 + l16) * 64 +
                                                   (((ks * 4 + quad) ^ x7) << 3)];
            __builtin_amdgcn_s_setprio(1);
            #pragma unroll
            for (int mt = 0; mt < 4; mt++)
                #pragma unroll
                for (int nt = 0; nt < 4; nt++)
                    acc[mt][nt] = __builtin_amdgcn_mfma_f32_16x16x32_bf16(
                        a[mt], bfr[nt], acc[mt][nt], 0, 0, 0);
            __builtin_amdgcn_s_setprio(0);
        }
        __syncthreads();
        cur ^= 1;
    }

    float* pbase = part + ((size_t)(mat * NTILE + tile) * SPLITK + chunk) * 16384;
    #pragma unroll
    for (int mt = 0; mt < 4; mt++)
        #pragma unroll
        for (int nt = 0; nt < 4; nt++)
            #pragma unroll
            for (int rj = 0; rj < 4; rj++) {
                int rr2 = wrow + mt * 16 + quad * 4 + rj;
                int cc2 = wcol + nt * 16 + l16;
                pbase[rr2 * 128 + cc2] = acc[mt][nt][rj];
            }
}

// K3: fold part for BOTH matrices per slice, apply stats, accumulate loss.
// 448 blocks = 14 tiles x 32 slices (>=1 block/CU). XX -> term1; XM -> term2;
// block 0 adds term3.
__global__ __launch_bounds__(256) void k_reduce(const float* __restrict__ part,
                                                const float* __restrict__ mu_a,
                                                const float* __restrict__ mu_b,
                                                const float* __restrict__ rs_a,
                                                const float* __restrict__ rs_b,
                                                const int* __restrict__ counts,
                                                float* __restrict__ out) {
    __shared__ float red[8];
    int bid = blockIdx.x;                // 0..447
    int tile = bid >> 5, sub = bid & 31;
    int t = threadIdx.x;
    int e2 = sub * 512 + t * 2;

    const float2* pa = (const float2*)(part +
        ((size_t)tile * SPLITK) * 16384 + e2);
    const float2* pb = (const float2*)(part +
        ((size_t)(NTILE + tile) * SPLITK) * 16384 + e2);
    float2 Sa = make_float2(0.f, 0.f);
    float2 Sb = make_float2(0.f, 0.f);
    #pragma unroll
    for (int c = 0; c < SPLITK; c++) {
        float2 va = pa[(size_t)c * 8192];
        float2 vb = pb[(size_t)c * 8192];
        Sa.x += va.x; Sa.y += va.y;
        Sb.x += vb.x; Sb.y += vb.y;
    }

    int rw = e2 >> 7, cl = e2 & 127;
    float local = 0.f;
    float scale;
    if (tile < NXT) {
        int gi = c_ti[tile] * 128 + rw;
        int gj = c_tj[tile] * 128 + cl;
        float mai = mu_a[gi], rai = rs_a[gi];
        float mbi = mu_b[gi], rbi = rs_b[gi];
        float2 maj = *(const float2*)&mu_a[gj];
        float2 raj = *(const float2*)&rs_a[gj];
        float2 mbj = *(const float2*)&mu_b[gj];
        float2 rbj = *(const float2*)&rs_b[gj];
        float ga, gb;
        ga = rai * raj.x * (Sa.x - (float)NN * mai * maj.x);
        gb = rbi * rbj.x * (Sb.x - (float)NN * mbi * mbj.x);
        local += ga * gb;
        ga = rai * raj.y * (Sa.y - (float)NN * mai * maj.y);
        gb = rbi * rbj.y * (Sb.y - (float)NN * mbi * mbj.y);
        local += ga * gb;
        scale = c_w[tile] * (1.0f / ((float)DD * (float)DD));
    } else {
        int k = (tile - NXT) * 128 + rw;
        float mak = mu_a[k], rak = rs_a[k];
        float mbk = mu_b[k], rbk = rs_b[k];
        int2 cn = *(const int2*)&counts[cl];
        float ta, tb;
        ta = rak * (Sa.x - (float)cn.x * mak);
        tb = rbk * (Sb.x - (float)cn.x * mbk);
        local += ta * tb;
        ta = rak * (Sa.y - (float)cn.y * mak);
        tb = rbk * (Sb.y - (float)cn.y * mbk);
        local += ta * tb;
        scale = -2.0f / (float)DD;
    }

    float s = block_reduce_sum_p(local, red);
    if (t == 0) {
        float add = s * scale;
        if (bid == 0) {
            float t3 = 0.f;
            for (int cc2 = 0; cc2 < NC; cc2++) {
                float nc = (float)counts[cc2];
                t3 += nc * nc;
            }
            add += t3;
        }
        atomicAdd(out, add);
    }
}

extern "C" void kernel_launch(void* const* d_in, const int* in_sizes, int n_in,
                              void* d_out, int out_size, void* d_ws, size_t ws_size,
                              hipStream_t stream) {
    const float* z_a = (const float*)d_in[0];
    const float* z_b = (const float*)d_in[1];
    const int* labels = (const int*)d_in[2];
    float* out = (float*)d_out;
    char* wsb = (char*)d_ws;

    float* cpsum = (float*)(wsb + CPS_B);
    float* cpsq = (float*)(wsb + CPQ_B);
    float* mu_a = (float*)(wsb + MUA_B);
    float* mu_b = (float*)(wsb + MUB_B);
    float* rs_a = (float*)(wsb + RSA_B);
    float* rs_b = (float*)(wsb + RSB_B);
    int* counts = (int*)(wsb + CNT_B);
    short* XTa = (short*)(wsb + XTA_B);
    short* XTb = (short*)(wsb + XTB_B);
    short* MT = (short*)(wsb + MT_B);
    float* part = (float*)(wsb + PART_B);

    hipLaunchKernelGGL(k_prep, dim3(2177), dim3(256), 0, stream,
                       z_a, z_b, labels, XTa, XTb, MT, cpsum, cpsq, counts, out);
    hipLaunchKernelGGL(k_gram, dim3(450), dim3(256), 0, stream,
                       XTa, XTb, MT, part, cpsum, cpsq, mu_a, mu_b, rs_a, rs_b);
    hipLaunchKernelGGL(k_reduce, dim3(448), dim3(256), 0, stream,
                       part, mu_a, mu_b, rs_a, rs_b, counts, out);
}